// Round 1
// baseline (259.168 us; speedup 1.0000x reference)
//
#include <hip/hip_runtime.h>

// Output layout (flat, in reference return order):
//   [0,               mapsz)   boundary map  [B, D, N, N]
//   [mapsz,         2*mapsz)   content  map  [B, D, N, N]
//   [2*mapsz, 2*mapsz+B*N*N)   mask          [B, 1, N, N]  (bool -> 0.0/1.0 f32)
// with N = 64, B = 16, D = 512, mapsz = B*D*N*N.

__device__ __forceinline__ bool on_line(int i, int off) {
    // off = j - i > 0. Membership per POOLING_COUNTS=[15,8,8], N=64:
    //   group0: stride 1, offsets 1..15, any i
    //   group1: stride 2, offsets 17,19,..,31 (odd), i even
    //   group2: stride 4, offsets 35,39,..,63 (==3 mod 4), i % 4 == 0
    return (off <= 15)
        || ((off & 1) && off >= 17 && off <= 31 && !(i & 1))
        || (((off & 3) == 3) && off >= 35 && !(i & 3));
}

__global__ __launch_bounds__(256) void sbc_kernel(const float* __restrict__ x,
                                                  float* __restrict__ out,
                                                  size_t mapsz) {
    __shared__ float sp[7][64];   // sparse max table: sp[k][t] = max x[t .. t+2^k-1]
    const int bd = blockIdx.x;    // bd = b*512 + d
    const int t  = threadIdx.x;

    if (t < 64) sp[0][t] = x[(size_t)bd * 64 + t];
    __syncthreads();
#pragma unroll
    for (int k = 1; k < 7; ++k) {
        if (t < 64) {
            const int w = 1 << (k - 1);
            float v = sp[k - 1][t];
            if (t + w < 64) v = fmaxf(v, sp[k - 1][t + w]);
            sp[k][t] = v;
        }
        __syncthreads();
    }

    const size_t bbase = (size_t)bd * 4096;
#pragma unroll
    for (int it = 0; it < 4; ++it) {
        const int p4 = t + it * 256;   // float4 index within the 64x64 tile
        const int p  = p4 << 2;
        const int i  = p >> 6;
        const int j0 = p & 63;
        const float xi = sp[0][i];
        float bb[4], cc[4];
#pragma unroll
        for (int q = 0; q < 4; ++q) {
            const int j = j0 + q;
            float b = 0.0f, c = 0.0f;
            if (j == i) {
                b = xi; c = xi;
            } else if (j > i) {
                const int off = j - i;
                if (on_line(i, off)) {
                    b = 0.5f * (xi + sp[0][j]);
                    const int k = 31 - __clz(off + 1);          // floor(log2(len))
                    c = fmaxf(sp[k][i], sp[k][j + 1 - (1 << k)]); // max x[i..j]
                }
            }
            bb[q] = b; cc[q] = c;
        }
        *(float4*)(out + bbase + p)         = make_float4(bb[0], bb[1], bb[2], bb[3]);
        *(float4*)(out + mapsz + bbase + p) = make_float4(cc[0], cc[1], cc[2], cc[3]);
    }

    // mask: one copy per batch; emitted by the d==0 block of each batch
    if ((bd & 511) == 0) {
        const int b = bd >> 9;
        float* mout = out + 2 * mapsz + (size_t)b * 4096;
#pragma unroll
        for (int it = 0; it < 4; ++it) {
            const int p4 = t + it * 256;
            const int p  = p4 << 2;
            const int i  = p >> 6;
            const int j0 = p & 63;
            float mm[4];
#pragma unroll
            for (int q = 0; q < 4; ++q) {
                const int j = j0 + q;
                bool on = (j == i) || (j > i && on_line(i, j - i));
                mm[q] = on ? 1.0f : 0.0f;
            }
            *(float4*)(mout + p) = make_float4(mm[0], mm[1], mm[2], mm[3]);
        }
    }
}

extern "C" void kernel_launch(void* const* d_in, const int* in_sizes, int n_in,
                              void* d_out, int out_size, void* d_ws, size_t ws_size,
                              hipStream_t stream) {
    const float* x = (const float*)d_in[0];
    float* out = (float*)d_out;
    const int N  = 64;
    const int BD = in_sizes[0] / N;                 // 16*512 = 8192
    const size_t mapsz = (size_t)BD * N * N;        // 33,554,432 elements
    sbc_kernel<<<dim3(BD), dim3(256), 0, stream>>>(x, out, mapsz);
}

// Round 2
// 255.282 us; speedup vs baseline: 1.0152x; 1.0152x over previous
//
#include <hip/hip_runtime.h>

// Output layout (flat, reference return order), N=64, B=16, D=512:
//   [0,       mapsz)          boundary [B,D,N,N]
//   [mapsz, 2*mapsz)          content  [B,D,N,N]
//   [2*mapsz, 2*mapsz+B*N*N)  mask     [B,1,N,N] (0.0/1.0 f32)
//
// Identities (verified R1): content[i,j] = max(x[i..j]) on member lines,
// boundary[i,j] = 0.5*(x[i]+x[j]); diagonal is the len=1 special case of both.

#define TPB 256
#define T_TILES 8

__device__ __forceinline__ bool on_line(int i, int off) {
    // off = j-i >= 1. POOLING_COUNTS=[15,8,8], N=64:
    //  g0: off 1..15, any i | g1: off odd 17..31, i even | g2: off%4==3, 35..63, i%4==0
    return (off <= 15)
        || ((off & 1) && off >= 17 && off <= 31 && !(i & 1))
        || (((off & 3) == 3) && off >= 35 && !(i & 3));
}

__global__ __launch_bounds__(TPB) void sbc_kernel(const float* __restrict__ x,
                                                  float* __restrict__ out,
                                                  size_t mapsz) {
    __shared__ float sp[7][64];   // sp[k][t] = max x[t .. t+2^k-1]
    const int t   = threadIdx.x;
    const int bd0 = blockIdx.x * T_TILES;

    // ---- static per-thread metadata: 16 elements = 4 groups of float4 ----
    int   ioff[4], joff[4];          // LDS byte offsets: sp[0][i], sp[0][j0] (b128)
    int   c0off[4][4], c1off[4][4];  // content gather byte offsets into sp
    float s[4][4];                   // 0.5 if on mask (incl diag), else 0
#pragma unroll
    for (int g = 0; g < 4; ++g) {
        const int p  = (t + g * 256) << 2;   // element index in 64x64 tile
        const int i  = p >> 6;
        const int j0 = p & 63;
        ioff[g] = i << 2;
        joff[g] = j0 << 2;
#pragma unroll
        for (int q = 0; q < 4; ++q) {
            const int j = j0 + q;
            const bool m = (j == i) || (j > i && on_line(i, j - i));
            if (m) {
                const int len = j - i + 1;
                const int k   = 31 - __clz(len);          // floor(log2(len))
                c0off[g][q] = (k << 8) + (i << 2);        // &sp[k][i]
                c1off[g][q] = (k << 8) + ((j + 1 - (1 << k)) << 2);
                s[g][q] = 0.5f;
            } else {
                c0off[g][q] = 0; c1off[g][q] = 0; s[g][q] = 0.0f;
            }
        }
    }

    // ---- preload all 8 tiles' x rows (wave 0 only), pay latency once ----
    float xv[T_TILES];
    if (t < 64) {
#pragma unroll
        for (int tt = 0; tt < T_TILES; ++tt)
            xv[tt] = x[(size_t)(bd0 + tt) * 64 + t];
    }

    const char* spb = (const char*)&sp[0][0];

#pragma unroll
    for (int tt = 0; tt < T_TILES; ++tt) {
        // build sparse-max table: Hillis-Steele suffix-window max via shfl_down
        if (t < 64) {
            float v = xv[tt];
            sp[0][t] = v;
            int w = 1;
#pragma unroll
            for (int k = 1; k < 7; ++k) {
                const float v2 = __shfl_down(v, w, 64);
                v = fmaxf(v, v2);      // garbage in slots t+2^k-1 > 63: never read
                sp[k][t] = v;
                w <<= 1;
            }
        }
        __syncthreads();

        const size_t base = (size_t)(bd0 + tt) * 4096;
#pragma unroll
        for (int g = 0; g < 4; ++g) {
            const int p = (t + g * 256) << 2;
            const float  xi  = *(const float*)(spb + ioff[g]);
            const float4 xj4 = *(const float4*)(spb + joff[g]);
            float4 bv, cv;
            bv.x = s[g][0] * (xi + xj4.x);
            bv.y = s[g][1] * (xi + xj4.y);
            bv.z = s[g][2] * (xi + xj4.z);
            bv.w = s[g][3] * (xi + xj4.w);
            cv.x = (s[g][0] + s[g][0]) * fmaxf(*(const float*)(spb + c0off[g][0]),
                                               *(const float*)(spb + c1off[g][0]));
            cv.y = (s[g][1] + s[g][1]) * fmaxf(*(const float*)(spb + c0off[g][1]),
                                               *(const float*)(spb + c1off[g][1]));
            cv.z = (s[g][2] + s[g][2]) * fmaxf(*(const float*)(spb + c0off[g][2]),
                                               *(const float*)(spb + c1off[g][2]));
            cv.w = (s[g][3] + s[g][3]) * fmaxf(*(const float*)(spb + c0off[g][3]),
                                               *(const float*)(spb + c1off[g][3]));
            *(float4*)(out + base + p)         = bv;
            *(float4*)(out + mapsz + base + p) = cv;
        }
        __syncthreads();   // sp rewritten next tile
    }

    // ---- mask: one copy per batch, written by the block owning d==0 ----
    if ((bd0 & 511) == 0) {
        float* mout = out + 2 * mapsz + (size_t)(bd0 >> 9) * 4096;
#pragma unroll
        for (int g = 0; g < 4; ++g) {
            const int p = (t + g * 256) << 2;
            *(float4*)(mout + p) = make_float4(s[g][0] + s[g][0], s[g][1] + s[g][1],
                                               s[g][2] + s[g][2], s[g][3] + s[g][3]);
        }
    }
}

extern "C" void kernel_launch(void* const* d_in, const int* in_sizes, int n_in,
                              void* d_out, int out_size, void* d_ws, size_t ws_size,
                              hipStream_t stream) {
    const float* x = (const float*)d_in[0];
    float* out = (float*)d_out;
    const int N  = 64;
    const int BD = in_sizes[0] / N;                 // 8192
    const size_t mapsz = (size_t)BD * N * N;        // 33,554,432
    sbc_kernel<<<dim3(BD / T_TILES), dim3(TPB), 0, stream>>>(x, out, mapsz);
}

// Round 3
// 250.291 us; speedup vs baseline: 1.0355x; 1.0199x over previous
//
#include <hip/hip_runtime.h>

// Output layout (flat, reference return order), N=64, B=16, D=512:
//   [0,       mapsz)          boundary [B,D,N,N]
//   [mapsz, 2*mapsz)          content  [B,D,N,N]
//   [2*mapsz, 2*mapsz+B*N*N)  mask     [B,1,N,N] (0.0/1.0 f32)
//
// Identities (verified R1/R2): on member lines content[i,j] = max(x[i..j]),
// boundary[i,j] = 0.5*(x[i]+x[j]); the diagonal is the len=1 case of both.
//
// Structure: one wave per 64x64 tile, lane = column j. Running max over
// descending row i gives content with no gathers; membership is a per-lane
// 64-bit constant; no LDS, no barriers -> stores pipeline freely.

#define T_PER_WAVE 2   // tiles per wave: 8192 tiles / 2 = 4096 waves = 1024 blocks

__global__ __launch_bounds__(256) void sbc_kernel(const float* __restrict__ x,
                                                  float* __restrict__ out,
                                                  size_t mapsz) {
    const int lane = threadIdx.x & 63;               // column j
    const int wid  = blockIdx.x * 4 + (threadIdx.x >> 6);
    const int j    = lane;

    // Membership bitmask for column j: bit i set iff (i,j) is on the mask.
    //  diag: i==j
    //  g0: off=j-i in 1..15, any i          (rev const: bits 48..62)
    //  g1: off odd in 17..31, i even        (rev const: bits 32,34..46, & even-i)
    //  g2: off%4==3 in 35..63, i%4==0       (rev const: bits 0,4..28,  & i%4==0)
    const int sh = 63 - j;
    const unsigned long long mbits =
          (1ULL << j)
        | (0x7FFF000000000000ULL >> sh)
        | ((0x0000555500000000ULL >> sh) & 0x5555555555555555ULL)
        | ((0x0000000011111111ULL >> sh) & 0x1111111111111111ULL);

    const int tile0 = wid * T_PER_WAVE;

    // Preload this wave's tiles (256 B coalesced each), latencies overlapped.
    float xv[T_PER_WAVE];
#pragma unroll
    for (int tt = 0; tt < T_PER_WAVE; ++tt)
        xv[tt] = x[(size_t)(tile0 + tt) * 64 + j];

#pragma unroll
    for (int tt = 0; tt < T_PER_WAVE; ++tt) {
        const int tile = tile0 + tt;
        float* __restrict__ bout = out + (size_t)tile * 4096;
        float* __restrict__ cout = bout + mapsz;
        const float xj = xv[tt];
        float r = xj;   // finite init: masked lanes never see -inf
#pragma unroll
        for (int i = 63; i >= 0; --i) {
            const float xi = __shfl(xv[tt], i, 64);      // uniform -> v_readlane
            // running max of x[i..j], only once i enters [0, j]
            const float xs = (j >= i) ? xi : -INFINITY;
            r = fmaxf(r, xs);
            const bool on  = (mbits >> i) & 1ULL;
            const float s  = on ? 0.5f : 0.0f;
            const float s2 = on ? 1.0f : 0.0f;
            bout[i * 64 + j] = s * (xi + xj);
            cout[i * 64 + j] = s2 * r;
        }
        // mask: one copy per batch, owned by the tile with d==0
        if ((tile & 511) == 0) {
            float* __restrict__ mout = out + 2 * mapsz + (size_t)(tile >> 9) * 4096;
#pragma unroll
            for (int i = 0; i < 64; ++i)
                mout[i * 64 + j] = ((mbits >> i) & 1ULL) ? 1.0f : 0.0f;
        }
    }
}

extern "C" void kernel_launch(void* const* d_in, const int* in_sizes, int n_in,
                              void* d_out, int out_size, void* d_ws, size_t ws_size,
                              hipStream_t stream) {
    const float* x = (const float*)d_in[0];
    float* out = (float*)d_out;
    const int N  = 64;
    const int BD = in_sizes[0] / N;                   // 8192 tiles
    const size_t mapsz = (size_t)BD * N * N;          // 33,554,432
    const int nwaves = BD / T_PER_WAVE;               // 4096
    sbc_kernel<<<dim3(nwaves / 4), dim3(256), 0, stream>>>(x, out, mapsz);
}